// Round 4
// baseline (874.348 us; speedup 1.0000x reference)
//
#include <hip/hip_runtime.h>

#define T_STEPS 120
#define NF_IN   180
#define H_DIM   128
#define G_DIM   512
#define K_FC    192
#define HP      136   // h_lds row stride (shorts)

#define L2E      1.4426950408889634f
#define TWO_L2E  2.8853900817779268f

typedef __attribute__((ext_vector_type(8))) short short8;
typedef __attribute__((ext_vector_type(4))) float f32x4;

// barrier WITHOUT vmcnt drain: LDS-ordering only. Global loads/stores stay in
// flight across steps (HIP __syncthreads drains vmcnt(0) -> ~900cyc/step stall).
#define LDS_BARRIER() asm volatile("s_waitcnt lgkmcnt(0)\ns_barrier" ::: "memory")

#if __has_builtin(__builtin_amdgcn_exp2f)
#define EXP2(x) __builtin_amdgcn_exp2f(x)
#else
#define EXP2(x) __expf((x) * 0.6931471805599453f)
#endif

__device__ __forceinline__ f32x4 mfma16(short8 a, short8 b, f32x4 c) {
    return __builtin_amdgcn_mfma_f32_16x16x32_bf16(a, b, c, 0, 0, 0);
}

__device__ __forceinline__ short f2bf(float x) {
    union { float f; unsigned u; } v; v.f = x;
    unsigned r = v.u + 0x7fffu + ((v.u >> 16) & 1u);
    return (short)(r >> 16);
}

// gate-sign AND log2e folded into weights at prep time:
//   i,f,o rows * (-log2e)  -> sigmoid(x) = rcp(1 + exp2(y))
//   g rows    * (+2*log2e) -> tanh(x)    = 1 - 2*rcp(1 + exp2(y))
__device__ __forceinline__ float sig2(float y) {
    return __builtin_amdgcn_rcpf(1.f + EXP2(y));
}
__device__ __forceinline__ float tanh2(float y) {
    return 1.f - 2.f * __builtin_amdgcn_rcpf(1.f + EXP2(y));
}

// ---------------- K1: weight prep (BN fold + bf16 + gate-sign/log2e folding) -
__global__ void prep_kernel(
    const float* __restrict__ fc_w, const float* __restrict__ fc_b,
    const float* __restrict__ bn_g, const float* __restrict__ bn_b,
    const float* __restrict__ bn_mean, const float* __restrict__ bn_var,
    const float* __restrict__ wih0, const float* __restrict__ whh0,
    const float* __restrict__ bih0, const float* __restrict__ bhh0,
    const float* __restrict__ wih1, const float* __restrict__ whh1,
    const float* __restrict__ bih1, const float* __restrict__ bhh1,
    short* __restrict__ fcw_o, float* __restrict__ fcb_o,
    float* __restrict__ bias0_o, float* __restrict__ bias1_o,
    short* __restrict__ wih0_o, short* __restrict__ whh0_o,
    short* __restrict__ wih1_o, short* __restrict__ whh1_o,
    int* __restrict__ prog_o)
{
    int tid = blockIdx.x * blockDim.x + threadIdx.x;
    int stride = gridDim.x * blockDim.x;
    for (int i = tid; i < 256; i += stride) prog_o[i] = 0;   // pipeline flags reset (per graph replay)
    for (int i = tid; i < H_DIM * K_FC; i += stride) {
        int h = i / K_FC, f = i % K_FC;
        float s = bn_g[h] * rsqrtf(bn_var[h] + 1e-5f);
        float v = (f < NF_IN) ? fc_w[h * NF_IN + f] * s : 0.f;
        fcw_o[i] = f2bf(v);
    }
    for (int i = tid; i < H_DIM; i += stride) {
        float s = bn_g[i] * rsqrtf(bn_var[i] + 1e-5f);
        fcb_o[i] = (fc_b[i] - bn_mean[i]) * s + bn_b[i];
    }
    for (int i = tid; i < G_DIM; i += stride) {
        float sc = ((i >> 7) == 2) ? TWO_L2E : -L2E;
        bias0_o[i] = (bih0[i] + bhh0[i]) * sc;
        bias1_o[i] = (bih1[i] + bhh1[i]) * sc;
    }
    for (int i = tid; i < G_DIM * H_DIM; i += stride) {
        float sc = ((i >> 7) / H_DIM == 2) ? TWO_L2E : -L2E;
        wih0_o[i] = f2bf(wih0[i] * sc); whh0_o[i] = f2bf(whh0[i] * sc);
        wih1_o[i] = f2bf(wih1[i] * sc); whh1_o[i] = f2bf(whh1[i] * sc);
    }
}

// ---------------- K2: fused FC + BN + LeakyReLU (r2 known-good version) ------
__global__ __launch_bounds__(256) void fc_kernel(
    const float* __restrict__ x, const short* __restrict__ fcw,
    const float* __restrict__ fcb, short* __restrict__ xfc)
{
    __shared__ short outs[120 * 132];
    const int b = blockIdx.x;
    const int tid = threadIdx.x;
    const int wave = tid >> 6, lane = tid & 63;
    const int m16 = lane & 15, q = lane >> 4;

    short8 af[2][6];
#pragma unroll
    for (int mi = 0; mi < 2; ++mi) {
        int t = (wave * 2 + mi) * 16 + m16;
        if (t > 119) t = 119;
        const float* xb = x + (size_t)b * (NF_IN * T_STEPS) + (size_t)q * 8 * T_STEPS + t;
#pragma unroll
        for (int kc = 0; kc < 6; ++kc) {
            union { short s[8]; short8 v; } u;
#pragma unroll
            for (int j = 0; j < 8; ++j) {
                int f = kc * 32 + q * 8 + j;
                float val = (f < NF_IN) ? xb[(kc * 32 + j) * T_STEPS] : 0.f;
                u.s[j] = f2bf(val);
            }
            af[mi][kc] = u.v;
        }
    }

    float fcb_v[8];
#pragma unroll
    for (int nt = 0; nt < 8; ++nt) fcb_v[nt] = fcb[nt * 16 + m16];

    f32x4 acc[2][8];
#pragma unroll
    for (int mi = 0; mi < 2; ++mi)
#pragma unroll
        for (int nt = 0; nt < 8; ++nt) acc[mi][nt] = (f32x4){0.f, 0.f, 0.f, 0.f};

#pragma unroll
    for (int nt = 0; nt < 8; ++nt) {
        short8 bf[6];
#pragma unroll
        for (int kc = 0; kc < 6; ++kc)
            bf[kc] = *(const short8*)(fcw + (nt * 16 + m16) * K_FC + kc * 32 + q * 8);
#pragma unroll
        for (int mi = 0; mi < 2; ++mi)
#pragma unroll
            for (int kc = 0; kc < 6; ++kc)
                acc[mi][nt] = mfma16(af[mi][kc], bf[kc], acc[mi][nt]);
    }

#pragma unroll
    for (int mi = 0; mi < 2; ++mi)
#pragma unroll
        for (int nt = 0; nt < 8; ++nt)
#pragma unroll
            for (int r = 0; r < 4; ++r) {
                int t = (wave * 2 + mi) * 16 + q * 4 + r;
                int h = nt * 16 + m16;
                float v = acc[mi][nt][r] + fcb_v[nt];
                v = (v >= 0.f) ? v : 0.01f * v;
                if (t < 120) outs[t * 132 + h] = f2bf(v);
            }
    __syncthreads();

    unsigned* dst = (unsigned*)xfc + (size_t)b * (T_STEPS * H_DIM / 2);
    const unsigned* srcs = (const unsigned*)outs;
    for (int i = tid; i < T_STEPS * H_DIM / 2; i += 256) {
        int t = i >> 6, c2 = i & 63;
        dst[i] = srcs[t * 66 + c2];
    }
}

// ---------------- K3: BOTH LSTM layers, producer/consumer pipelined ----------
// Grid = 2*(B/16) = 256 blocks x 512 thr. Blocks [0,128): layer 0 (producer)
// on batch rows [16*pb, 16*pb+16); blocks [128,256): layer 1 (consumer) on the
// same rows, lagging ~3 steps. All 256 blocks are co-resident (1 block/CU) so
// the spin-wait cannot deadlock regardless of dispatch placement.
//
// M=16 MFMA tiles (16 batch rows): proj's C/D layout == rec's C/D layout
// (m=batch=(lane>>4)*4+r, n=dim=lane&15) -> xp feeds rec's C-init directly,
// no cross-lane shuffles, update runs on all 64 lanes.
//
// Handoff (cross-XCD safe): producer exports h0(s) into hpub (=bufA, aliased:
// slot t is read as x_fc at phase t-2 and written as h0 at phase t+1) with
// RELAXED AGENT atomic stores (coherent point, no L2 wb fence). Every 2 steps:
// per-wave s_waitcnt vmcnt(4) (exports are OLDER than the 4 in-flight prefetch
// loads -> counted wait drains exports only), barrier, tid0 flag store.
// Consumer spins on the flag (relaxed agent atomic) and reads h0 frags with
// AGENT atomic loads (bypass the stale clean copy the same-XCD producer's
// x_fc reads may have left in L2).
__global__ __launch_bounds__(512, 2) void lstm_fused_kernel(
    const short* __restrict__ xfc,   // bufA: fc output (producer A-input)
    short* hpub,                     // = bufA aliased (h0 publish target)
    const short* __restrict__ wih0b, const short* __restrict__ whh0b,
    const float* __restrict__ bias0,
    const short* __restrict__ wih1b, const short* __restrict__ whh1b,
    const float* __restrict__ bias1,
    int* prog, float* __restrict__ fout)
{
    __shared__ short h_lds[2 * 16 * HP];

    const int tid = threadIdx.x;
    const int w = tid >> 6, lane = tid & 63;
    const int m16 = lane & 15, q = lane >> 4;
    const int role = blockIdx.x >> 7;          // 0 = layer0 producer, 1 = layer1 consumer
    const int pb   = blockIdx.x & 127;
    const int b0   = pb * 16;

    const short* wih  = role ? wih1b : wih0b;
    const short* whh  = role ? whh1b : whh0b;
    const float* bias = role ? bias1 : bias0;

    // zero both h double-buffers (2*16*HP shorts = 2176 uints)
    for (int i = tid; i < 8 * HP; i += 512) {
        ((unsigned*)h_lds)[i] = 0u;
        ((unsigned*)h_lds)[i + 8 * HP] = 0u;
    }

    short8 whf[4][4], wif[4][4];
    float bias_v[4];
#pragma unroll
    for (int g = 0; g < 4; ++g) {
        int n = g * 128 + w * 16 + m16;
        bias_v[g] = bias[n];
#pragma unroll
        for (int kc = 0; kc < 4; ++kc) {
            whf[g][kc] = *(const short8*)(whh + n * H_DIM + kc * 32 + q * 8);
            wif[g][kc] = *(const short8*)(wih + n * H_DIM + kc * 32 + q * 8);
        }
    }

    float c[4] = {0.f, 0.f, 0.f, 0.f};   // cell*2log2e: batch row q*4+r, dim w*16+m16
    f32x4 P[4];                          // xp for the NEXT step (incl. bias), all 4 gates
    short8 axc[4], axn[4];               // A-frags (x_fc or h0) for upcoming projs

    // A-frag load for input at step t. Producer: plain loads from x_fc.
    // Consumer: agent atomic loads from hpub (L1/L2 bypass -> fresh h0).
    auto loadX = [&](short8 ax[4], int t) {
        if (t > T_STEPS - 1) t = T_STEPS - 1;
        if (!role) {
            const short* src = xfc + ((size_t)(b0 + m16) * T_STEPS + t) * H_DIM + q * 8;
#pragma unroll
            for (int kc = 0; kc < 4; ++kc) ax[kc] = *(const short8*)(src + kc * 32);
        } else {
            const unsigned* src = (const unsigned*)hpub
                + ((size_t)(b0 + m16) * T_STEPS + t) * (H_DIM / 2) + q * 4;
#pragma unroll
            for (int kc = 0; kc < 4; ++kc) {
                union { unsigned u[4]; short8 v; } uu;
#pragma unroll
                for (int jj = 0; jj < 4; ++jj)
                    uu.u[jj] = __hip_atomic_load(src + kc * 16 + jj,
                                                 __ATOMIC_RELAXED, __HIP_MEMORY_SCOPE_AGENT);
                ax[kc] = uu.v;
            }
        }
    };

    // proj for ONE step t -> registers P (M=16 rows = all batch rows)
    auto projP = [&](const short8 ax[4]) {
#pragma unroll
        for (int g = 0; g < 4; ++g) {
            float bv = bias_v[g];
            f32x4 acc = (f32x4){bv, bv, bv, bv};
#pragma unroll
            for (int kc = 0; kc < 4; ++kc) acc = mfma16(ax[kc], wif[g][kc], acc);
            P[g] = acc;
        }
    };

    // rec matmul (C-init = P) + gate/cell update (all 64 lanes) + h write
    auto recUpdate = [&](int s, int rb, int hb) {
        const short* rbp = h_lds + rb * (16 * HP) + m16 * HP + q * 8;
        short8 ar[4];
#pragma unroll
        for (int kc = 0; kc < 4; ++kc) ar[kc] = *(const short8*)(rbp + kc * 32);
        f32x4 a0 = P[0], a1 = P[1], a2 = P[2], a3 = P[3];
#pragma unroll
        for (int kc = 0; kc < 4; ++kc) {
            a0 = mfma16(ar[kc], whf[0][kc], a0);
            a1 = mfma16(ar[kc], whf[1][kc], a1);
            a2 = mfma16(ar[kc], whf[2][kc], a2);
            a3 = mfma16(ar[kc], whf[3][kc], a3);
        }
        float hv[4];
#pragma unroll
        for (int r = 0; r < 4; ++r) {
            float i_ = sig2(a0[r]);
            float f_ = sig2(a1[r]);
            float g_ = __builtin_fmaf(-2.f * TWO_L2E,
                                      __builtin_amdgcn_rcpf(1.f + EXP2(a2[r])),
                                      TWO_L2E);
            float o_ = sig2(a3[r]);
            c[r] = f_ * c[r] + i_ * g_;
            hv[r] = o_ * tanh2(c[r]);
        }
        short* hw = h_lds + hb * (16 * HP) + (q * 4) * HP + (w * 16 + m16);
#pragma unroll
        for (int r = 0; r < 4; ++r) hw[r * HP] = f2bf(hv[r]);
        if (role && s == T_STEPS - 1) {
#pragma unroll
            for (int r = 0; r < 4; ++r)
                fout[(size_t)(b0 + q * 4 + r) * H_DIM + w * 16 + m16] = hv[r];
        }
    };

    // producer: publish h(s) (in LDS buf hb) -> hpub slot s, write-through
    auto exportH = [&](int s, int hb) {
        const unsigned* srcu = (const unsigned*)h_lds + hb * (8 * HP);
        unsigned* dstu = (unsigned*)hpub;
#pragma unroll
        for (int i = tid; i < 16 * 64; i += 512) {
            int row = i >> 6, col = i & 63;
            unsigned v = srcu[row * (HP / 2) + col];
            __hip_atomic_store(dstu + ((size_t)(b0 + row) * T_STEPS + s) * 64 + col,
                               v, __ATOMIC_RELAXED, __HIP_MEMORY_SCOPE_AGENT);
        }
    };

    auto waitProg = [&](int target) {   // consumer spin: slots [0,target) ready
        if (target > 120) target = 120;
        while (__hip_atomic_load(prog + pb, __ATOMIC_RELAXED,
                                 __HIP_MEMORY_SCOPE_AGENT) < target)
            __builtin_amdgcn_s_sleep(2);
    };

    // prologue: P <- xp(0); axc <- input(1)
    if (!role) {
        loadX(axn, 0); projP(axn);
        loadX(axc, 1);
    } else {
        waitProg(1); loadX(axn, 0); projP(axn);
        waitProg(2); loadX(axc, 1);
    }
    LDS_BARRIER();

    for (int it = 0; it < T_STEPS / 2; ++it) {
        const int s = 2 * it;
        // ---- even phase: h(s-1) in buf1 -> h(s) in buf0 ---------------------
        recUpdate(s, 1, 0);
        projP(axc);                       // P <- xp(s+1)
        if (!role) { if (s >= 1) exportH(s - 1, 1); }
        else waitProg(s + 3);
        loadX(axn, s + 2);
        LDS_BARRIER();
        // ---- odd phase: h(s) in buf0 -> h(s+1) in buf1 ----------------------
        recUpdate(s + 1, 0, 1);
        projP(axn);                       // P <- xp(s+2)
        if (!role) exportH(s, 0);
        else waitProg(s + 4);
        loadX(axc, s + 3);
        if (!role) asm volatile("s_waitcnt vmcnt(4)" ::: "memory");  // drain exports only
        LDS_BARRIER();
        if (!role && tid == 0)
            __hip_atomic_store(prog + pb, s + 1,
                               __ATOMIC_RELAXED, __HIP_MEMORY_SCOPE_AGENT);
    }
    if (!role) {   // tail: publish h(119)
        exportH(T_STEPS - 1, 1);
        asm volatile("s_waitcnt vmcnt(0)" ::: "memory");
        LDS_BARRIER();
        if (tid == 0)
            __hip_atomic_store(prog + pb, 120,
                               __ATOMIC_RELAXED, __HIP_MEMORY_SCOPE_AGENT);
    }
}

// ---------------- launch ----------------
static constexpr size_t OFF_FCW  = 0;
static constexpr size_t OFF_FCB  = 49152;
static constexpr size_t OFF_B0   = 49664;
static constexpr size_t OFF_B1   = 51712;
static constexpr size_t OFF_WIH0 = 53760;
static constexpr size_t OFF_WHH0 = 184832;
static constexpr size_t OFF_WIH1 = 315904;
static constexpr size_t OFF_WHH1 = 446976;
static constexpr size_t OFF_PROG = 578048;
static constexpr size_t OFF_BUFA = 579072;

extern "C" void kernel_launch(void* const* d_in, const int* in_sizes, int n_in,
                              void* d_out, int out_size, void* d_ws, size_t ws_size,
                              hipStream_t stream) {
    const float* x       = (const float*)d_in[0];
    const float* fc_w    = (const float*)d_in[1];
    const float* fc_b    = (const float*)d_in[2];
    const float* bn_g    = (const float*)d_in[3];
    const float* bn_b    = (const float*)d_in[4];
    const float* bn_mean = (const float*)d_in[5];
    const float* bn_var  = (const float*)d_in[6];
    const float* wih0    = (const float*)d_in[7];
    const float* whh0    = (const float*)d_in[8];
    const float* bih0    = (const float*)d_in[9];
    const float* bhh0    = (const float*)d_in[10];
    const float* wih1    = (const float*)d_in[11];
    const float* whh1    = (const float*)d_in[12];
    const float* bih1    = (const float*)d_in[13];
    const float* bhh1    = (const float*)d_in[14];

    const int B = in_sizes[0] / (NF_IN * T_STEPS);   // 2048

    char* ws = (char*)d_ws;
    short* fcw   = (short*)(ws + OFF_FCW);
    float* fcb   = (float*)(ws + OFF_FCB);
    float* bias0 = (float*)(ws + OFF_B0);
    float* bias1 = (float*)(ws + OFF_B1);
    short* wih0b = (short*)(ws + OFF_WIH0);
    short* whh0b = (short*)(ws + OFF_WHH0);
    short* wih1b = (short*)(ws + OFF_WIH1);
    short* whh1b = (short*)(ws + OFF_WHH1);
    int*   prog  = (int*)  (ws + OFF_PROG);
    short* bufA  = (short*)(ws + OFF_BUFA);

    prep_kernel<<<256, 256, 0, stream>>>(
        fc_w, fc_b, bn_g, bn_b, bn_mean, bn_var,
        wih0, whh0, bih0, bhh0, wih1, whh1, bih1, bhh1,
        fcw, fcb, bias0, bias1, wih0b, whh0b, wih1b, whh1b, prog);

    fc_kernel<<<B, 256, 0, stream>>>(x, fcw, fcb, bufA);

    lstm_fused_kernel<<<(B / 16) * 2, 512, 0, stream>>>(
        bufA, bufA, wih0b, whh0b, bias0, wih1b, whh1b, bias1,
        prog, (float*)d_out);
}

// Round 5
// 673.435 us; speedup vs baseline: 1.2983x; 1.2983x over previous
//
#include <hip/hip_runtime.h>

#define T_STEPS 120
#define NF_IN   180
#define H_DIM   128
#define G_DIM   512
#define K_FC    192
#define HP      136   // h_lds row stride (shorts)

#define L2E      1.4426950408889634f
#define TWO_L2E  2.8853900817779268f

typedef __attribute__((ext_vector_type(8))) short short8;
typedef __attribute__((ext_vector_type(4))) float f32x4;

// barrier WITHOUT vmcnt drain: LDS-ordering only. Global loads/stores stay in
// flight across steps (HIP __syncthreads drains vmcnt(0) -> ~900cyc/step stall).
#define LDS_BARRIER() asm volatile("s_waitcnt lgkmcnt(0)\ns_barrier" ::: "memory")

#if __has_builtin(__builtin_amdgcn_exp2f)
#define EXP2(x) __builtin_amdgcn_exp2f(x)
#else
#define EXP2(x) __expf((x) * 0.6931471805599453f)
#endif

__device__ __forceinline__ f32x4 mfma16(short8 a, short8 b, f32x4 c) {
    return __builtin_amdgcn_mfma_f32_16x16x32_bf16(a, b, c, 0, 0, 0);
}

__device__ __forceinline__ short f2bf(float x) {
    union { float f; unsigned u; } v; v.f = x;
    unsigned r = v.u + 0x7fffu + ((v.u >> 16) & 1u);
    return (short)(r >> 16);
}

// gate-sign AND log2e folded into weights at prep time:
//   i,f,o rows * (-log2e)  -> sigmoid(x) = rcp(1 + exp2(y))
//   g rows    * (+2*log2e) -> tanh(x)    = 1 - 2*rcp(1 + exp2(y))
__device__ __forceinline__ float sig2(float y) {
    return __builtin_amdgcn_rcpf(1.f + EXP2(y));
}
__device__ __forceinline__ float tanh2(float y) {
    return 1.f - 2.f * __builtin_amdgcn_rcpf(1.f + EXP2(y));
}

// ---------------- K1: weight prep (BN fold + bf16 + gate-sign/log2e folding) -
__global__ void prep_kernel(
    const float* __restrict__ fc_w, const float* __restrict__ fc_b,
    const float* __restrict__ bn_g, const float* __restrict__ bn_b,
    const float* __restrict__ bn_mean, const float* __restrict__ bn_var,
    const float* __restrict__ wih0, const float* __restrict__ whh0,
    const float* __restrict__ bih0, const float* __restrict__ bhh0,
    const float* __restrict__ wih1, const float* __restrict__ whh1,
    const float* __restrict__ bih1, const float* __restrict__ bhh1,
    short* __restrict__ fcw_o, float* __restrict__ fcb_o,
    float* __restrict__ bias0_o, float* __restrict__ bias1_o,
    short* __restrict__ wih0_o, short* __restrict__ whh0_o,
    short* __restrict__ wih1_o, short* __restrict__ whh1_o,
    int* __restrict__ prog_o)
{
    int tid = blockIdx.x * blockDim.x + threadIdx.x;
    int stride = gridDim.x * blockDim.x;
    for (int i = tid; i < 256; i += stride) prog_o[i] = 0;   // pipeline flags reset (per graph replay)
    for (int i = tid; i < H_DIM * K_FC; i += stride) {
        int h = i / K_FC, f = i % K_FC;
        float s = bn_g[h] * rsqrtf(bn_var[h] + 1e-5f);
        float v = (f < NF_IN) ? fc_w[h * NF_IN + f] * s : 0.f;
        fcw_o[i] = f2bf(v);
    }
    for (int i = tid; i < H_DIM; i += stride) {
        float s = bn_g[i] * rsqrtf(bn_var[i] + 1e-5f);
        fcb_o[i] = (fc_b[i] - bn_mean[i]) * s + bn_b[i];
    }
    for (int i = tid; i < G_DIM; i += stride) {
        float sc = ((i >> 7) == 2) ? TWO_L2E : -L2E;
        bias0_o[i] = (bih0[i] + bhh0[i]) * sc;
        bias1_o[i] = (bih1[i] + bhh1[i]) * sc;
    }
    for (int i = tid; i < G_DIM * H_DIM; i += stride) {
        float sc = ((i >> 7) / H_DIM == 2) ? TWO_L2E : -L2E;
        wih0_o[i] = f2bf(wih0[i] * sc); whh0_o[i] = f2bf(whh0[i] * sc);
        wih1_o[i] = f2bf(wih1[i] * sc); whh1_o[i] = f2bf(whh1[i] * sc);
    }
}

// ---------------- K2: fused FC + BN + LeakyReLU (r2 known-good version) ------
__global__ __launch_bounds__(256) void fc_kernel(
    const float* __restrict__ x, const short* __restrict__ fcw,
    const float* __restrict__ fcb, short* __restrict__ xfc)
{
    __shared__ short outs[120 * 132];
    const int b = blockIdx.x;
    const int tid = threadIdx.x;
    const int wave = tid >> 6, lane = tid & 63;
    const int m16 = lane & 15, q = lane >> 4;

    short8 af[2][6];
#pragma unroll
    for (int mi = 0; mi < 2; ++mi) {
        int t = (wave * 2 + mi) * 16 + m16;
        if (t > 119) t = 119;
        const float* xb = x + (size_t)b * (NF_IN * T_STEPS) + (size_t)q * 8 * T_STEPS + t;
#pragma unroll
        for (int kc = 0; kc < 6; ++kc) {
            union { short s[8]; short8 v; } u;
#pragma unroll
            for (int j = 0; j < 8; ++j) {
                int f = kc * 32 + q * 8 + j;
                float val = (f < NF_IN) ? xb[(kc * 32 + j) * T_STEPS] : 0.f;
                u.s[j] = f2bf(val);
            }
            af[mi][kc] = u.v;
        }
    }

    float fcb_v[8];
#pragma unroll
    for (int nt = 0; nt < 8; ++nt) fcb_v[nt] = fcb[nt * 16 + m16];

    f32x4 acc[2][8];
#pragma unroll
    for (int mi = 0; mi < 2; ++mi)
#pragma unroll
        for (int nt = 0; nt < 8; ++nt) acc[mi][nt] = (f32x4){0.f, 0.f, 0.f, 0.f};

#pragma unroll
    for (int nt = 0; nt < 8; ++nt) {
        short8 bf[6];
#pragma unroll
        for (int kc = 0; kc < 6; ++kc)
            bf[kc] = *(const short8*)(fcw + (nt * 16 + m16) * K_FC + kc * 32 + q * 8);
#pragma unroll
        for (int mi = 0; mi < 2; ++mi)
#pragma unroll
            for (int kc = 0; kc < 6; ++kc)
                acc[mi][nt] = mfma16(af[mi][kc], bf[kc], acc[mi][nt]);
    }

#pragma unroll
    for (int mi = 0; mi < 2; ++mi)
#pragma unroll
        for (int nt = 0; nt < 8; ++nt)
#pragma unroll
            for (int r = 0; r < 4; ++r) {
                int t = (wave * 2 + mi) * 16 + q * 4 + r;
                int h = nt * 16 + m16;
                float v = acc[mi][nt][r] + fcb_v[nt];
                v = (v >= 0.f) ? v : 0.01f * v;
                if (t < 120) outs[t * 132 + h] = f2bf(v);
            }
    __syncthreads();

    unsigned* dst = (unsigned*)xfc + (size_t)b * (T_STEPS * H_DIM / 2);
    const unsigned* srcs = (const unsigned*)outs;
    for (int i = tid; i < T_STEPS * H_DIM / 2; i += 256) {
        int t = i >> 6, c2 = i & 63;
        dst[i] = srcs[t * 66 + c2];
    }
}

// ---------------- K3: BOTH LSTM layers, producer/consumer pipelined ----------
// Grid = 2*(B/16) = 256 blocks x 512 thr (co-resident at 1 block/CU -> no
// deadlock). Blocks [0,128): layer 0 on 16 batch rows; [128,256): layer 1 on
// the same rows, lagging ~12 steps.
//
// r4 lesson: per-phase flag ping-pong (LLC round trip every phase) killed it.
// This version amortizes ALL handoff cost to 8-step windows:
//   - producer: exports h0(s) each step as ONE 8B agent-atomic store/thread;
//     drains vmcnt(0) + sets prog ONCE per 8 steps (prog = 8,16,...,112,116,120)
//   - consumer: ONE waitProg per 8 phases (target s+12, ~12-step lag);
//     h0 frag loads = 8B agent-atomic loads issued 2-3 phases before use
//     (LLC latency hidden by the lag)
__global__ __launch_bounds__(512, 2) void lstm_fused_kernel(
    const short* __restrict__ xfc,   // bufA: fc output (producer A-input)
    short* hpub,                     // = bufA aliased (h0 publish target)
    const short* __restrict__ wih0b, const short* __restrict__ whh0b,
    const float* __restrict__ bias0,
    const short* __restrict__ wih1b, const short* __restrict__ whh1b,
    const float* __restrict__ bias1,
    int* prog, float* __restrict__ fout)
{
    __shared__ short h_lds[2 * 16 * HP];

    const int tid = threadIdx.x;
    const int w = tid >> 6, lane = tid & 63;
    const int m16 = lane & 15, q = lane >> 4;
    const int role = blockIdx.x >> 7;          // 0 = layer0 producer, 1 = layer1 consumer
    const int pb   = blockIdx.x & 127;
    const int b0   = pb * 16;

    const short* wih  = role ? wih1b : wih0b;
    const short* whh  = role ? whh1b : whh0b;
    const float* bias = role ? bias1 : bias0;

    // zero both h double-buffers
    for (int i = tid; i < 8 * HP; i += 512) {
        ((unsigned*)h_lds)[i] = 0u;
        ((unsigned*)h_lds)[i + 8 * HP] = 0u;
    }

    short8 whf[4][4], wif[4][4];
    float bias_v[4];
#pragma unroll
    for (int g = 0; g < 4; ++g) {
        int n = g * 128 + w * 16 + m16;
        bias_v[g] = bias[n];
#pragma unroll
        for (int kc = 0; kc < 4; ++kc) {
            whf[g][kc] = *(const short8*)(whh + n * H_DIM + kc * 32 + q * 8);
            wif[g][kc] = *(const short8*)(wih + n * H_DIM + kc * 32 + q * 8);
        }
    }

    float c[4] = {0.f, 0.f, 0.f, 0.f};   // cell*2log2e: batch row q*4+r, dim w*16+m16
    f32x4 P[4];                          // xp for the NEXT step (incl. bias)
    short8 axc[4], axn[4];               // A-frags for upcoming projs

    // A-frag load for input at step t. Producer: plain cached b128 loads from
    // x_fc. Consumer: 8B agent-atomic loads from hpub (coherent at LLC).
    auto loadX = [&](short8 ax[4], int t) {
        if (t > T_STEPS - 1) t = T_STEPS - 1;
        if (!role) {
            const short* src = xfc + ((size_t)(b0 + m16) * T_STEPS + t) * H_DIM + q * 8;
#pragma unroll
            for (int kc = 0; kc < 4; ++kc) ax[kc] = *(const short8*)(src + kc * 32);
        } else {
            const unsigned long long* src = (const unsigned long long*)hpub
                + ((size_t)(b0 + m16) * T_STEPS + t) * 32 + q * 2;
#pragma unroll
            for (int kc = 0; kc < 4; ++kc) {
                union { unsigned long long u[2]; short8 v; } uu;
                uu.u[0] = __hip_atomic_load(src + kc * 8 + 0,
                                            __ATOMIC_RELAXED, __HIP_MEMORY_SCOPE_AGENT);
                uu.u[1] = __hip_atomic_load(src + kc * 8 + 1,
                                            __ATOMIC_RELAXED, __HIP_MEMORY_SCOPE_AGENT);
                ax[kc] = uu.v;
            }
        }
    };

    // proj for ONE step -> registers P (M=16 rows = all batch rows)
    auto projP = [&](const short8 ax[4]) {
#pragma unroll
        for (int g = 0; g < 4; ++g) {
            float bv = bias_v[g];
            f32x4 acc = (f32x4){bv, bv, bv, bv};
#pragma unroll
            for (int kc = 0; kc < 4; ++kc) acc = mfma16(ax[kc], wif[g][kc], acc);
            P[g] = acc;
        }
    };

    // rec matmul (C-init = P) + gate/cell update (all 64 lanes) + h write
    auto recUpdate = [&](int s, int rb, int hb) {
        const short* rbp = h_lds + rb * (16 * HP) + m16 * HP + q * 8;
        short8 ar[4];
#pragma unroll
        for (int kc = 0; kc < 4; ++kc) ar[kc] = *(const short8*)(rbp + kc * 32);
        f32x4 a0 = P[0], a1 = P[1], a2 = P[2], a3 = P[3];
#pragma unroll
        for (int kc = 0; kc < 4; ++kc) {
            a0 = mfma16(ar[kc], whf[0][kc], a0);
            a1 = mfma16(ar[kc], whf[1][kc], a1);
            a2 = mfma16(ar[kc], whf[2][kc], a2);
            a3 = mfma16(ar[kc], whf[3][kc], a3);
        }
        float hv[4];
#pragma unroll
        for (int r = 0; r < 4; ++r) {
            float i_ = sig2(a0[r]);
            float f_ = sig2(a1[r]);
            float g_ = __builtin_fmaf(-2.f * TWO_L2E,
                                      __builtin_amdgcn_rcpf(1.f + EXP2(a2[r])),
                                      TWO_L2E);
            float o_ = sig2(a3[r]);
            c[r] = f_ * c[r] + i_ * g_;
            hv[r] = o_ * tanh2(c[r]);
        }
        short* hw = h_lds + hb * (16 * HP) + (q * 4) * HP + (w * 16 + m16);
#pragma unroll
        for (int r = 0; r < 4; ++r) hw[r * HP] = f2bf(hv[r]);
        if (role && s == T_STEPS - 1) {
#pragma unroll
            for (int r = 0; r < 4; ++r)
                fout[(size_t)(b0 + q * 4 + r) * H_DIM + w * 16 + m16] = hv[r];
        }
    };

    // producer: publish h(s) (LDS buf hb) -> hpub slot s. 512 ull / 512 thr =
    // one 8B agent-atomic store per thread (write-through to LLC).
    auto exportH = [&](int s, int hb) {
        const unsigned long long* srcu = (const unsigned long long*)h_lds + hb * (4 * HP);
        int row = tid >> 5, col = tid & 31;
        unsigned long long v = srcu[row * (HP / 4) + col];
        __hip_atomic_store((unsigned long long*)hpub
                               + ((size_t)(b0 + row) * T_STEPS + s) * 32 + col,
                           v, __ATOMIC_RELAXED, __HIP_MEMORY_SCOPE_AGENT);
    };

    auto waitProg = [&](int target) {   // spin: slots [0,target) ready
        if (target > 120) target = 120;
        while (__hip_atomic_load(prog + pb, __ATOMIC_RELAXED,
                                 __HIP_MEMORY_SCOPE_AGENT) < target)
            __builtin_amdgcn_s_sleep(4);
    };

    // prologue: P <- xp(0); axc <- input(1)
    if (!role) {
        loadX(axn, 0); projP(axn);
        loadX(axc, 1);
    } else {
        waitProg(12);           // one wait covers slots [0,12): prologue + first window
        loadX(axn, 0); projP(axn);
        loadX(axc, 1);
    }
    LDS_BARRIER();

    for (int it = 0; it < T_STEPS / 2; ++it) {
        const int s = 2 * it;
        if (role && s && (s & 7) == 0) waitProg(s + 12);   // 1 flag wait / 8 phases
        // ---- even phase: h(s-1) buf1 -> h(s) buf0 ---------------------------
        recUpdate(s, 1, 0);
        projP(axc);                       // P <- xp(s+1)
        if (!role && s >= 1) exportH(s - 1, 1);
        loadX(axn, s + 2);
        LDS_BARRIER();
        // ---- odd phase: h(s) buf0 -> h(s+1) buf1 ----------------------------
        recUpdate(s + 1, 0, 1);
        projP(axn);                       // P <- xp(s+2)
        if (!role) exportH(s, 0);
        loadX(axc, s + 3);
        if (!role && ((((s + 2) & 7) == 0 && s + 2 <= 112) || s + 2 == 116)) {
            // window end: drain exports to LLC, then publish progress
            asm volatile("s_waitcnt vmcnt(0)" ::: "memory");
            LDS_BARRIER();
            if (tid == 0)
                __hip_atomic_store(prog + pb, s + 2,
                                   __ATOMIC_RELAXED, __HIP_MEMORY_SCOPE_AGENT);
        } else {
            LDS_BARRIER();
        }
    }
    if (!role) {   // tail: publish h(119), final flag
        exportH(T_STEPS - 1, 1);
        asm volatile("s_waitcnt vmcnt(0)" ::: "memory");
        LDS_BARRIER();
        if (tid == 0)
            __hip_atomic_store(prog + pb, 120,
                               __ATOMIC_RELAXED, __HIP_MEMORY_SCOPE_AGENT);
    }
}

// ---------------- launch ----------------
static constexpr size_t OFF_FCW  = 0;
static constexpr size_t OFF_FCB  = 49152;
static constexpr size_t OFF_B0   = 49664;
static constexpr size_t OFF_B1   = 51712;
static constexpr size_t OFF_WIH0 = 53760;
static constexpr size_t OFF_WHH0 = 184832;
static constexpr size_t OFF_WIH1 = 315904;
static constexpr size_t OFF_WHH1 = 446976;
static constexpr size_t OFF_PROG = 578048;
static constexpr size_t OFF_BUFA = 579072;

extern "C" void kernel_launch(void* const* d_in, const int* in_sizes, int n_in,
                              void* d_out, int out_size, void* d_ws, size_t ws_size,
                              hipStream_t stream) {
    const float* x       = (const float*)d_in[0];
    const float* fc_w    = (const float*)d_in[1];
    const float* fc_b    = (const float*)d_in[2];
    const float* bn_g    = (const float*)d_in[3];
    const float* bn_b    = (const float*)d_in[4];
    const float* bn_mean = (const float*)d_in[5];
    const float* bn_var  = (const float*)d_in[6];
    const float* wih0    = (const float*)d_in[7];
    const float* whh0    = (const float*)d_in[8];
    const float* bih0    = (const float*)d_in[9];
    const float* bhh0    = (const float*)d_in[10];
    const float* wih1    = (const float*)d_in[11];
    const float* whh1    = (const float*)d_in[12];
    const float* bih1    = (const float*)d_in[13];
    const float* bhh1    = (const float*)d_in[14];

    const int B = in_sizes[0] / (NF_IN * T_STEPS);   // 2048

    char* ws = (char*)d_ws;
    short* fcw   = (short*)(ws + OFF_FCW);
    float* fcb   = (float*)(ws + OFF_FCB);
    float* bias0 = (float*)(ws + OFF_B0);
    float* bias1 = (float*)(ws + OFF_B1);
    short* wih0b = (short*)(ws + OFF_WIH0);
    short* whh0b = (short*)(ws + OFF_WHH0);
    short* wih1b = (short*)(ws + OFF_WIH1);
    short* whh1b = (short*)(ws + OFF_WHH1);
    int*   prog  = (int*)  (ws + OFF_PROG);
    short* bufA  = (short*)(ws + OFF_BUFA);

    prep_kernel<<<256, 256, 0, stream>>>(
        fc_w, fc_b, bn_g, bn_b, bn_mean, bn_var,
        wih0, whh0, bih0, bhh0, wih1, whh1, bih1, bhh1,
        fcw, fcb, bias0, bias1, wih0b, whh0b, wih1b, whh1b, prog);

    fc_kernel<<<B, 256, 0, stream>>>(x, fcw, fcb, bufA);

    lstm_fused_kernel<<<(B / 16) * 2, 512, 0, stream>>>(
        bufA, bufA, wih0b, whh0b, bias0, wih1b, whh1b, bias1,
        prog, (float*)d_out);
}

// Round 6
// 632.644 us; speedup vs baseline: 1.3821x; 1.0645x over previous
//
#include <hip/hip_runtime.h>

#define T_STEPS 120
#define NF_IN   180
#define H_DIM   128
#define G_DIM   512
#define K_FC    192
#define HP      136   // h_lds row stride (shorts)
#define XPR     12    // xp row-group stride in floats (8 rows + 4 pad; 48B -> 16B-aligned, 2-way banks)

#define L2E      1.4426950408889634f
#define TWO_L2E  2.8853900817779268f

typedef __attribute__((ext_vector_type(8))) short short8;
typedef __attribute__((ext_vector_type(4))) float f32x4;

// barrier WITHOUT vmcnt drain: LDS-ordering only. Global loads/stores stay in
// flight across steps (HIP __syncthreads drains vmcnt(0) -> ~900cyc/step stall).
#define LDS_BARRIER() asm volatile("s_waitcnt lgkmcnt(0)\ns_barrier" ::: "memory")

#if __has_builtin(__builtin_amdgcn_exp2f)
#define EXP2(x) __builtin_amdgcn_exp2f(x)
#else
#define EXP2(x) __expf((x) * 0.6931471805599453f)
#endif

__device__ __forceinline__ f32x4 mfma16(short8 a, short8 b, f32x4 c) {
    return __builtin_amdgcn_mfma_f32_16x16x32_bf16(a, b, c, 0, 0, 0);
}

__device__ __forceinline__ short f2bf(float x) {
    union { float f; unsigned u; } v; v.f = x;
    unsigned r = v.u + 0x7fffu + ((v.u >> 16) & 1u);
    return (short)(r >> 16);
}

// gate-sign AND log2e folded into weights at prep time:
//   i,f,o rows * (-log2e)  -> sigmoid(x) = rcp(1 + exp2(y))
//   g rows    * (+2*log2e) -> tanh(x)    = 1 - 2*rcp(1 + exp2(y))
__device__ __forceinline__ float sig2(float y) {
    return __builtin_amdgcn_rcpf(1.f + EXP2(y));
}
__device__ __forceinline__ float tanh2(float y) {
    return 1.f - 2.f * __builtin_amdgcn_rcpf(1.f + EXP2(y));
}

// ---------------- K1: weight prep (BN fold + bf16 + gate-sign/log2e folding) -
__global__ void prep_kernel(
    const float* __restrict__ fc_w, const float* __restrict__ fc_b,
    const float* __restrict__ bn_g, const float* __restrict__ bn_b,
    const float* __restrict__ bn_mean, const float* __restrict__ bn_var,
    const float* __restrict__ wih0, const float* __restrict__ whh0,
    const float* __restrict__ bih0, const float* __restrict__ bhh0,
    const float* __restrict__ wih1, const float* __restrict__ whh1,
    const float* __restrict__ bih1, const float* __restrict__ bhh1,
    short* __restrict__ fcw_o, float* __restrict__ fcb_o,
    float* __restrict__ bias0_o, float* __restrict__ bias1_o,
    short* __restrict__ wih0_o, short* __restrict__ whh0_o,
    short* __restrict__ wih1_o, short* __restrict__ whh1_o)
{
    int tid = blockIdx.x * blockDim.x + threadIdx.x;
    int stride = gridDim.x * blockDim.x;
    for (int i = tid; i < H_DIM * K_FC; i += stride) {
        int h = i / K_FC, f = i % K_FC;
        float s = bn_g[h] * rsqrtf(bn_var[h] + 1e-5f);
        float v = (f < NF_IN) ? fc_w[h * NF_IN + f] * s : 0.f;
        fcw_o[i] = f2bf(v);
    }
    for (int i = tid; i < H_DIM; i += stride) {
        float s = bn_g[i] * rsqrtf(bn_var[i] + 1e-5f);
        fcb_o[i] = (fc_b[i] - bn_mean[i]) * s + bn_b[i];
    }
    for (int i = tid; i < G_DIM; i += stride) {
        float sc = ((i >> 7) == 2) ? TWO_L2E : -L2E;
        bias0_o[i] = (bih0[i] + bhh0[i]) * sc;
        bias1_o[i] = (bih1[i] + bhh1[i]) * sc;
    }
    for (int i = tid; i < G_DIM * H_DIM; i += stride) {
        float sc = ((i >> 7) / H_DIM == 2) ? TWO_L2E : -L2E;
        wih0_o[i] = f2bf(wih0[i] * sc); whh0_o[i] = f2bf(whh0[i] * sc);
        wih1_o[i] = f2bf(wih1[i] * sc); whh1_o[i] = f2bf(whh1[i] * sc);
    }
}

// ---------------- K2: fused FC + BN + LeakyReLU (r2 known-good version) ------
__global__ __launch_bounds__(256) void fc_kernel(
    const float* __restrict__ x, const short* __restrict__ fcw,
    const float* __restrict__ fcb, short* __restrict__ xfc)
{
    __shared__ short outs[120 * 132];
    const int b = blockIdx.x;
    const int tid = threadIdx.x;
    const int wave = tid >> 6, lane = tid & 63;
    const int m16 = lane & 15, q = lane >> 4;

    short8 af[2][6];
#pragma unroll
    for (int mi = 0; mi < 2; ++mi) {
        int t = (wave * 2 + mi) * 16 + m16;
        if (t > 119) t = 119;
        const float* xb = x + (size_t)b * (NF_IN * T_STEPS) + (size_t)q * 8 * T_STEPS + t;
#pragma unroll
        for (int kc = 0; kc < 6; ++kc) {
            union { short s[8]; short8 v; } u;
#pragma unroll
            for (int j = 0; j < 8; ++j) {
                int f = kc * 32 + q * 8 + j;
                float val = (f < NF_IN) ? xb[(kc * 32 + j) * T_STEPS] : 0.f;
                u.s[j] = f2bf(val);
            }
            af[mi][kc] = u.v;
        }
    }

    float fcb_v[8];
#pragma unroll
    for (int nt = 0; nt < 8; ++nt) fcb_v[nt] = fcb[nt * 16 + m16];

    f32x4 acc[2][8];
#pragma unroll
    for (int mi = 0; mi < 2; ++mi)
#pragma unroll
        for (int nt = 0; nt < 8; ++nt) acc[mi][nt] = (f32x4){0.f, 0.f, 0.f, 0.f};

#pragma unroll
    for (int nt = 0; nt < 8; ++nt) {
        short8 bf[6];
#pragma unroll
        for (int kc = 0; kc < 6; ++kc)
            bf[kc] = *(const short8*)(fcw + (nt * 16 + m16) * K_FC + kc * 32 + q * 8);
#pragma unroll
        for (int mi = 0; mi < 2; ++mi)
#pragma unroll
            for (int kc = 0; kc < 6; ++kc)
                acc[mi][nt] = mfma16(af[mi][kc], bf[kc], acc[mi][nt]);
    }

#pragma unroll
    for (int mi = 0; mi < 2; ++mi)
#pragma unroll
        for (int nt = 0; nt < 8; ++nt)
#pragma unroll
            for (int r = 0; r < 4; ++r) {
                int t = (wave * 2 + mi) * 16 + q * 4 + r;
                int h = nt * 16 + m16;
                float v = acc[mi][nt][r] + fcb_v[nt];
                v = (v >= 0.f) ? v : 0.01f * v;
                if (t < 120) outs[t * 132 + h] = f2bf(v);
            }
    __syncthreads();

    unsigned* dst = (unsigned*)xfc + (size_t)b * (T_STEPS * H_DIM / 2);
    const unsigned* srcs = (const unsigned*)outs;
    for (int i = tid; i < T_STEPS * H_DIM / 2; i += 256) {
        int t = i >> 6, c2 = i & 63;
        dst[i] = srcs[t * 66 + c2];
    }
}

// ---------------- K3: one LSTM layer, wave-specialized -----------------------
// 256 blocks x 1024 thr (16 waves = 4/SIMD -> 2x the latency hiding of r2's
// 2/SIMD). 8 batch rows/block.
//   waves 0-7  (rec): hold ONLY whh frags (64 VGPR). Per phase: read xp C-init
//     from the LDS ring + h(s-1), 16 MFMA, gate/cell update, write h(s).
//     This is the serial chain - nothing else rides on it.
//   waves 8-15 (proj): hold ONLY wih frags. Per 2-phase window: compute the
//     x-projection for pair (s+2,s+3) (16 MFMA), write into the ring; also
//     exportH + the global x loads (1-window lead hides HBM/L2 latency;
//     a proj stall never blocks rec waves).
// Ring xp_lds[slot=t&3][gate][dim][row(+pad)]: proj's MFMA D (f32x4 = rows
// q*4..+3 of its step-half at dim=lane&15) stores directly; rec reads the same
// f32x4 back as its MFMA C-init (M=8: lanes q<2 own rows). No transposes, no
// cross-lane ops. Slots s,s+1 are read while s+2,s+3 are written -> disjoint.
// Register discipline: wf[] and ab[] are ROLE-UNIONED so both paths share one
// allocation; __launch_bounds__(1024) forces a 4-wave/SIMD-launchable budget.
__global__ __launch_bounds__(1024) void lstm_kernel(
    const short* h_in, const short* __restrict__ wih,
    const short* __restrict__ whh, const float* __restrict__ bias,
    short* h_out, float* __restrict__ fout)
{
    __shared__ float xp_lds[4][4][H_DIM * XPR];   // 96 KB ring
    __shared__ short h_lds[2 * 8 * HP];           // 4.3 KB

    const int tid = threadIdx.x;
    const int w = tid >> 6, lane = tid & 63;
    const int m16 = lane & 15, q = lane >> 4, m8 = m16 & 7;
    const int wd = w & 7;
    const bool isRec = (w < 8);
    const int b0 = blockIdx.x * 8;
    const int dim = wd * 16 + m16;
    const int rowb = (q & 1) * 4;

    for (int i = tid; i < 8 * HP; i += 1024) ((unsigned*)h_lds)[i] = 0u;

    // role-unioned weight frags: rec <- whh, proj <- wih
    short8 wf[4][4];
    float bias_v[4];
    const short* wsrc = isRec ? whh : wih;
#pragma unroll
    for (int g = 0; g < 4; ++g) {
        int n = g * 128 + dim;
        bias_v[g] = bias[n];               // used by proj only
#pragma unroll
        for (int kc = 0; kc < 4; ++kc)
            wf[g][kc] = *(const short8*)(wsrc + n * H_DIM + kc * 32 + q * 8);
    }

    float c[4] = {0.f, 0.f, 0.f, 0.f};     // rec: cell*2log2e, rows q*4+r (q<2)
    short8 ab[4];                           // UNION: rec = ar (per phase), proj = x pair frags

    // ---- proj: load A-frags for pair (t1,t1+1): A rows 0-7 <- t1, 8-15 <- t1+1
    auto loadPair = [&](int t1) {
        int t = t1 + (m16 >> 3);
        if (t > T_STEPS - 1) t = T_STEPS - 1;
        const short* src = h_in + ((size_t)(b0 + m8) * T_STEPS + t) * H_DIM + q * 8;
#pragma unroll
        for (int kc = 0; kc < 4; ++kc) ab[kc] = *(const short8*)(src + kc * 32);
    };

    // ---- proj: 2 gates of pair (t1,t1+1) -> ring slots (t1&3),((t1+1)&3)
    auto projHalf = [&](int t1, int g0) {
        const int slot = (t1 + (q >> 1)) & 3;
#pragma unroll
        for (int gg = 0; gg < 2; ++gg) {
            int g = g0 + gg;
            float bv = bias_v[g];
            f32x4 acc = (f32x4){bv, bv, bv, bv};
#pragma unroll
            for (int kc = 0; kc < 4; ++kc) acc = mfma16(ab[kc], wf[g][kc], acc);
            *(f32x4*)&xp_lds[slot][g][dim * XPR + rowb] = acc;
        }
    };

    // ---- rec: full step s. h(s-1) in buf rb -> h(s) in buf hb.
    auto recPhase = [&](int s, int rb, int hb) {
        const int slot = s & 3;
        f32x4 a0 = *(const f32x4*)&xp_lds[slot][0][dim * XPR + rowb];
        f32x4 a1 = *(const f32x4*)&xp_lds[slot][1][dim * XPR + rowb];
        f32x4 a2 = *(const f32x4*)&xp_lds[slot][2][dim * XPR + rowb];
        f32x4 a3 = *(const f32x4*)&xp_lds[slot][3][dim * XPR + rowb];
        const short* rbp = h_lds + rb * (8 * HP) + m8 * HP + q * 8;
#pragma unroll
        for (int kc = 0; kc < 4; ++kc) ab[kc] = *(const short8*)(rbp + kc * 32);
#pragma unroll
        for (int kc = 0; kc < 4; ++kc) {
            a0 = mfma16(ab[kc], wf[0][kc], a0);
            a1 = mfma16(ab[kc], wf[1][kc], a1);
            a2 = mfma16(ab[kc], wf[2][kc], a2);
            a3 = mfma16(ab[kc], wf[3][kc], a3);
        }
        float hv[4];
#pragma unroll
        for (int r = 0; r < 4; ++r) {
            float i_ = sig2(a0[r]);
            float f_ = sig2(a1[r]);
            float g_ = __builtin_fmaf(-2.f * TWO_L2E,
                                      __builtin_amdgcn_rcpf(1.f + EXP2(a2[r])),
                                      TWO_L2E);
            float o_ = sig2(a3[r]);
            c[r] = f_ * c[r] + i_ * g_;
            hv[r] = o_ * tanh2(c[r]);
        }
        if (q < 2) {
            short* hw = h_lds + hb * (8 * HP) + (q * 4) * HP + dim;
#pragma unroll
            for (int r = 0; r < 4; ++r) hw[r * HP] = f2bf(hv[r]);
            if (fout != nullptr && s == T_STEPS - 1) {
#pragma unroll
                for (int r = 0; r < 4; ++r)
                    fout[(size_t)(b0 + q * 4 + r) * H_DIM + dim] = hv[r];
            }
        }
    };

    // ---- proj: coalesced h(s) -> global (512 proj threads, 512 uints)
    auto exportH = [&](int s, int hb) {
        int pt = tid & 511;
        int row = pt >> 6, c2 = pt & 63;
        unsigned v = ((const unsigned*)h_lds)[hb * (4 * HP) + row * (HP / 2) + c2];
        ((unsigned*)h_out)[((size_t)(b0 + row) * T_STEPS + s) * (H_DIM / 2) + c2] = v;
    };

    // prologue: proj fills slots 0,1 (pair(0,1)) and preloads pair(2,3)
    if (!isRec) {
        loadPair(0);
        projHalf(0, 0);
        projHalf(0, 2);
        loadPair(2);
    }
    LDS_BARRIER();

    for (int it = 0; it < T_STEPS / 2; ++it) {
        const int s = 2 * it;
        // ---- even phase ----------------------------------------------------
        if (isRec) {
            recPhase(s, 1, 0);                 // h(s-1) buf1 -> h(s) buf0
        } else {
            projHalf(s + 2, 0);                // gates 0,1 of pair(s+2,s+3)
            if (h_out != nullptr && s >= 1) exportH(s - 1, 1);
        }
        LDS_BARRIER();
        // ---- odd phase -----------------------------------------------------
        if (isRec) {
            recPhase(s + 1, 0, 1);             // h(s) buf0 -> h(s+1) buf1
        } else {
            projHalf(s + 2, 2);                // gates 2,3 of pair(s+2,s+3)
            if (h_out != nullptr) exportH(s, 0);
            loadPair(s + 4);                   // next window's x pair
        }
        LDS_BARRIER();
    }
    if (!isRec && h_out != nullptr) exportH(T_STEPS - 1, 1);
}

// ---------------- launch ----------------
static constexpr size_t OFF_FCW  = 0;
static constexpr size_t OFF_FCB  = 49152;
static constexpr size_t OFF_B0   = 49664;
static constexpr size_t OFF_B1   = 51712;
static constexpr size_t OFF_WIH0 = 53760;
static constexpr size_t OFF_WHH0 = 184832;
static constexpr size_t OFF_WIH1 = 315904;
static constexpr size_t OFF_WHH1 = 446976;
static constexpr size_t OFF_BUFA = 578048;

extern "C" void kernel_launch(void* const* d_in, const int* in_sizes, int n_in,
                              void* d_out, int out_size, void* d_ws, size_t ws_size,
                              hipStream_t stream) {
    const float* x       = (const float*)d_in[0];
    const float* fc_w    = (const float*)d_in[1];
    const float* fc_b    = (const float*)d_in[2];
    const float* bn_g    = (const float*)d_in[3];
    const float* bn_b    = (const float*)d_in[4];
    const float* bn_mean = (const float*)d_in[5];
    const float* bn_var  = (const float*)d_in[6];
    const float* wih0    = (const float*)d_in[7];
    const float* whh0    = (const float*)d_in[8];
    const float* bih0    = (const float*)d_in[9];
    const float* bhh0    = (const float*)d_in[10];
    const float* wih1    = (const float*)d_in[11];
    const float* whh1    = (const float*)d_in[12];
    const float* bih1    = (const float*)d_in[13];
    const float* bhh1    = (const float*)d_in[14];

    const int B = in_sizes[0] / (NF_IN * T_STEPS);   // 2048

    char* ws = (char*)d_ws;
    short* fcw   = (short*)(ws + OFF_FCW);
    float* fcb   = (float*)(ws + OFF_FCB);
    float* bias0 = (float*)(ws + OFF_B0);
    float* bias1 = (float*)(ws + OFF_B1);
    short* wih0b = (short*)(ws + OFF_WIH0);
    short* whh0b = (short*)(ws + OFF_WHH0);
    short* wih1b = (short*)(ws + OFF_WIH1);
    short* whh1b = (short*)(ws + OFF_WHH1);
    short* bufA  = (short*)(ws + OFF_BUFA);

    prep_kernel<<<256, 256, 0, stream>>>(
        fc_w, fc_b, bn_g, bn_b, bn_mean, bn_var,
        wih0, whh0, bih0, bhh0, wih1, whh1, bih1, bhh1,
        fcw, fcb, bias0, bias1, wih0b, whh0b, wih1b, whh1b);

    fc_kernel<<<B, 256, 0, stream>>>(x, fcw, fcb, bufA);

    lstm_kernel<<<B / 8, 1024, 0, stream>>>(bufA, wih0b, whh0b, bias0, bufA, nullptr);
    lstm_kernel<<<B / 8, 1024, 0, stream>>>(bufA, wih1b, whh1b, bias1, nullptr, (float*)d_out);
}